// Round 2
// baseline (3150.936 us; speedup 1.0000x reference)
//
#include <hip/hip_runtime.h>
#include <math.h>

#define NA   1024
#define NGRID 4096
#define NB   2
#define NG   (NB*NGRID)   // 8192
#define NN   (NA+NG)      // 9216
#define KAK  8
#define KGK  24
#define EAE  (NA*KAK)     // 8192
#define EGE  (NG*KGK)     // 196608
#define ET   (EAE+EGE)    // 204800
#define HD   240
#define TT   16
#define DIN  489
#define CD   32
#define CUTF 8.0f

__device__ __forceinline__ float silu_f(float x) {
    return x / (1.0f + __expf(-x));
}

// ---------------- kNN: atoms (K=8) ----------------
__global__ void knn_atoms_kernel(const float* __restrict__ pos, const int* __restrict__ batch,
                                 int* __restrict__ nbr) {
    __shared__ float sx[NA], sy[NA], sz[NA];
    __shared__ int   sb[NA];
    int tid = threadIdx.x;
    for (int j = tid; j < NA; j += blockDim.x) {
        sx[j] = pos[j*3+0]; sy[j] = pos[j*3+1]; sz[j] = pos[j*3+2]; sb[j] = batch[j];
    }
    __syncthreads();
    int i = blockIdx.x * blockDim.x + tid;
    float px = sx[i], py = sy[i], pz = sz[i];
    int b = sb[i];
    float bd[KAK]; int bi[KAK];
#pragma unroll
    for (int k = 0; k < KAK; ++k) { bd[k] = 3e38f; bi[k] = -1; }
    for (int j = 0; j < NA; ++j) {
        if (j == i || sb[j] != b) continue;
        float dx = px - sx[j], dy = py - sy[j], dz = pz - sz[j];
        float d2 = __fadd_rn(__fadd_rn(__fmul_rn(dx,dx), __fmul_rn(dy,dy)), __fmul_rn(dz,dz));
        if (d2 < bd[KAK-1]) {
            float d = d2; int id = j;
#pragma unroll
            for (int p = 0; p < KAK; ++p) {
                bool lt = d < bd[p];
                float td = bd[p]; int ti = bi[p];
                bd[p] = lt ? d : td; bi[p] = lt ? id : ti;
                d = lt ? td : d;   id = lt ? ti : id;
            }
        }
    }
#pragma unroll
    for (int k = 0; k < KAK; ++k) nbr[i*KAK+k] = bi[k];
}

// ---------------- kNN: grid (K=24) ----------------
__global__ void knn_grid_kernel(const float* __restrict__ pos, const int* __restrict__ batch,
                                int* __restrict__ nbg) {
    __shared__ float sx[NA], sy[NA], sz[NA];
    __shared__ int   sb[NA];
    int tid = threadIdx.x;
    for (int j = tid; j < NA; j += blockDim.x) {
        sx[j] = pos[j*3+0]; sy[j] = pos[j*3+1]; sz[j] = pos[j*3+2]; sb[j] = batch[j];
    }
    __syncthreads();
    int g = blockIdx.x * blockDim.x + tid;  // 0..8191
    int b  = g / NGRID;
    int gi = g % NGRID;
    int ix = gi >> 8, iy = (gi >> 4) & 15, iz = gi & 15;
    float px = ((float)ix - 7.5f) * 1.5f;
    float py = ((float)iy - 7.5f) * 1.5f;
    float pz = ((float)iz - 7.5f) * 1.5f;
    float bd[KGK]; int bi[KGK];
#pragma unroll
    for (int k = 0; k < KGK; ++k) { bd[k] = 3e38f; bi[k] = -1; }
    for (int j = 0; j < NA; ++j) {
        if (sb[j] != b) continue;
        float dx = px - sx[j], dy = py - sy[j], dz = pz - sz[j];
        float d2 = __fadd_rn(__fadd_rn(__fmul_rn(dx,dx), __fmul_rn(dy,dy)), __fmul_rn(dz,dz));
        if (d2 < bd[KGK-1]) {
            float d = d2; int id = j;
#pragma unroll
            for (int p = 0; p < KGK; ++p) {
                bool lt = d < bd[p];
                float td = bd[p]; int ti = bi[p];
                bd[p] = lt ? d : td; bi[p] = lt ? id : ti;
                d = lt ? td : d;   id = lt ? ti : id;
            }
        }
    }
#pragma unroll
    for (int k = 0; k < KGK; ++k) nbg[g*KGK+k] = bi[k];
}

// ---------------- edge features (sph * mask) ----------------
__global__ void edge_kernel(const float* __restrict__ pos, const int* __restrict__ nbr,
                            const int* __restrict__ nbg, float* __restrict__ ea,
                            float* __restrict__ emask) {
    int e = blockIdx.x * blockDim.x + threadIdx.x;
    if (e >= ET) return;
    int src; float dpx, dpy, dpz;
    if (e < EAE) {
        int d = e >> 3;
        src = nbr[e];
        dpx = pos[d*3]; dpy = pos[d*3+1]; dpz = pos[d*3+2];
    } else {
        int eg = e - EAE;
        src = nbg[eg];
        int gg = eg / KGK;
        int gi = gg % NGRID;
        int ix = gi >> 8, iy = (gi >> 4) & 15, iz = gi & 15;
        dpx = ((float)ix - 7.5f) * 1.5f;
        dpy = ((float)iy - 7.5f) * 1.5f;
        dpz = ((float)iz - 7.5f) * 1.5f;
    }
    float rx = pos[src*3] - dpx, ry = pos[src*3+1] - dpy, rz = pos[src*3+2] - dpz;
    float dist = sqrtf(rx*rx + ry*ry + rz*rz);
    float mask = (dist <= CUTF) ? 1.0f : 0.0f;
    float inv = 1.0f / fmaxf(dist, 1e-9f);
    float x = rx * inv, y = ry * inv, z = rz * inv;
    float s0 = 0.28209479177387814f;
    float s1 = 0.4886025119029199f * y;
    float s2 = 0.4886025119029199f * z;
    float s3 = 0.4886025119029199f * x;
    float s4 = 1.0925484305920792f * x * y;
    float s5 = 1.0925484305920792f * y * z;
    float s6 = 0.31539156525252005f * (3.0f * z * z - 1.0f);
    float s7 = 1.0925484305920792f * z * x;
    float s8 = 0.5462742152960396f * (x * x - y * y);
    float* o = &ea[(size_t)e * 9];
    o[0] = s0 * mask; o[1] = s1 * mask; o[2] = s2 * mask; o[3] = s3 * mask;
    o[4] = s4 * mask; o[5] = s5 * mask; o[6] = s6 * mask; o[7] = s7 * mask; o[8] = s8 * mask;
    emask[e] = mask;
}

// ---------------- node_attr (segment mean of ea) ----------------
__global__ void node_attr_kernel(const float* __restrict__ ea, const float* __restrict__ emask,
                                 float* __restrict__ attr) {
    int n = blockIdx.x * blockDim.x + threadIdx.x;
    if (n >= NN) return;
    int K, e0;
    if (n < NA) { K = KAK; e0 = n * KAK; }
    else        { K = KGK; e0 = EAE + (n - NA) * KGK; }
    float s[9];
#pragma unroll
    for (int a = 0; a < 9; ++a) s[a] = 0.f;
    float cnt = 0.f;
    for (int k = 0; k < K; ++k) {
        cnt += emask[e0 + k];
        const float* p = &ea[(size_t)(e0 + k) * 9];
#pragma unroll
        for (int a = 0; a < 9; ++a) s[a] += p[a];
    }
    float invc = 1.0f / fmaxf(cnt, 1.0f);
    attr[n*9+0] = 1.0f;
#pragma unroll
    for (int a = 1; a < 9; ++a) attr[n*9+a] = s[a] * invc;
}

// ---------------- encoder: h = silu([feat|attr] @ We + be) ----------------
__global__ void encoder_kernel(const int* __restrict__ types, const float* __restrict__ attr,
                               const float* __restrict__ We, const float* __restrict__ be,
                               float* __restrict__ h) {
    int idx = blockIdx.x * blockDim.x + threadIdx.x;  // n*HD + j
    int n = idx / HD, j = idx % HD;
    float acc = be[j];
    if (n < NA) acc += We[types[n] * HD + j];
#pragma unroll
    for (int a = 0; a < 9; ++a) acc += attr[n*9+a] * We[(TT + a) * HD + j];
    h[idx] = silu_f(acc);
}

// ---------------- message + aggregate, one block per dst node ----------------
template <int K>
__global__ void msg_kernel(const float* __restrict__ h, const int* __restrict__ nbrList,
                           const float* __restrict__ ea, const float* __restrict__ emask,
                           const float* __restrict__ Wm1, const float* __restrict__ bm1,
                           const float* __restrict__ Wm2, const float* __restrict__ bm2,
                           float* __restrict__ agg, int dstBase, int edgeBase) {
    __shared__ float hsrc[K][HD];
    __shared__ float hdst[HD];
    __shared__ float eas[K][12];
    __shared__ float m1s[K][HD];
    __shared__ float mk[K];
    int tid = threadIdx.x;
    int dn  = blockIdx.x;
    int dst = dstBase + dn;
    int e0  = edgeBase + dn * K;

    for (int i = tid; i < HD; i += 256) hdst[i] = h[(size_t)dst * HD + i];
    for (int idx = tid; idx < K * HD; idx += 256) {
        int k = idx / HD, i = idx % HD;
        int s = nbrList[dn * K + k];
        hsrc[k][i] = h[(size_t)s * HD + i];
    }
    // FIX (round 1): K*12 = 288 > 256 for K=24 — must loop, not predicate.
    for (int idx = tid; idx < K * 12; idx += 256) {
        int k = idx / 12, a = idx % 12;
        eas[k][a] = (a < 9) ? ea[(size_t)(e0 + k) * 9 + a] : 0.0f;
    }
    if (tid < K) mk[tid] = emask[e0 + tid];
    __syncthreads();

    int j = tid;
    if (j < HD) {
        float acc[K];
#pragma unroll
        for (int k = 0; k < K; ++k) acc[k] = 0.f;
        // part A: h[src] block (rows 0..239)
        for (int i4 = 0; i4 < 60; ++i4) {
            int i = 4 * i4;
            float w0 = Wm1[(i+0)*HD+j], w1 = Wm1[(i+1)*HD+j];
            float w2 = Wm1[(i+2)*HD+j], w3 = Wm1[(i+3)*HD+j];
#pragma unroll
            for (int k = 0; k < K; ++k) {
                const float4 a = *reinterpret_cast<const float4*>(&hsrc[k][i]);
                acc[k] += a.x*w0 + a.y*w1 + a.z*w2 + a.w*w3;
            }
        }
        // part B: h[dst] block (rows 240..479) — identical for all k edges
        float sdst = 0.f;
        for (int i4 = 0; i4 < 60; ++i4) {
            int i = 4 * i4;
            float w0 = Wm1[(240+i+0)*HD+j], w1 = Wm1[(240+i+1)*HD+j];
            float w2 = Wm1[(240+i+2)*HD+j], w3 = Wm1[(240+i+3)*HD+j];
            const float4 a = *reinterpret_cast<const float4*>(&hdst[i]);
            sdst += a.x*w0 + a.y*w1 + a.z*w2 + a.w*w3;
        }
        // part C: ea block (rows 480..488)
        for (int i4 = 0; i4 < 3; ++i4) {
            int i = 4 * i4;
            float w0 = (480+i+0 < DIN) ? Wm1[(480+i+0)*HD+j] : 0.f;
            float w1 = (480+i+1 < DIN) ? Wm1[(480+i+1)*HD+j] : 0.f;
            float w2 = (480+i+2 < DIN) ? Wm1[(480+i+2)*HD+j] : 0.f;
            float w3 = (480+i+3 < DIN) ? Wm1[(480+i+3)*HD+j] : 0.f;
#pragma unroll
            for (int k = 0; k < K; ++k) {
                const float4 a = *reinterpret_cast<const float4*>(&eas[k][i]);
                acc[k] += a.x*w0 + a.y*w1 + a.z*w2 + a.w*w3;
            }
        }
        float bb = bm1[j];
#pragma unroll
        for (int k = 0; k < K; ++k) m1s[k][j] = silu_f(acc[k] + sdst + bb);
    }
    __syncthreads();
    if (j < HD) {
        float acc[K];
#pragma unroll
        for (int k = 0; k < K; ++k) acc[k] = 0.f;
        for (int i4 = 0; i4 < 60; ++i4) {
            int i = 4 * i4;
            float w0 = Wm2[(i+0)*HD+j], w1 = Wm2[(i+1)*HD+j];
            float w2 = Wm2[(i+2)*HD+j], w3 = Wm2[(i+3)*HD+j];
#pragma unroll
            for (int k = 0; k < K; ++k) {
                const float4 a = *reinterpret_cast<const float4*>(&m1s[k][i]);
                acc[k] += a.x*w0 + a.y*w1 + a.z*w2 + a.w*w3;
            }
        }
        float bb = bm2[j];
        float sum = 0.f;
#pragma unroll
        for (int k = 0; k < K; ++k) sum += silu_f(acc[k] + bb) * mk[k];
        agg[(size_t)dst * HD + j] = sum;
    }
}

// ---------------- node update: h += MLP([h|agg|attr]) ----------------
__global__ void update_kernel(float* __restrict__ h, const float* __restrict__ agg,
                              const float* __restrict__ attr,
                              const float* __restrict__ Wu1, const float* __restrict__ bu1,
                              const float* __restrict__ Wu2, const float* __restrict__ bu2) {
    const int NBT = 4;
    __shared__ float ui[NBT][492];
    __shared__ float u1[NBT][HD];
    int tid = threadIdx.x;
    int n0 = blockIdx.x * NBT;
    for (int idx = tid; idx < NBT * 492; idx += 256) {
        int k = idx / 492, i = idx % 492;
        int n = n0 + k;
        float v;
        if (i < 240)      v = h[(size_t)n * HD + i];
        else if (i < 480) v = agg[(size_t)n * HD + (i - 240)];
        else if (i < 489) v = attr[n*9 + (i - 480)];
        else              v = 0.f;
        ui[k][i] = v;
    }
    __syncthreads();
    int j = tid;
    if (j < HD) {
        float acc[NBT] = {0.f, 0.f, 0.f, 0.f};
        for (int i4 = 0; i4 < 122; ++i4) {
            int i = 4 * i4;
            float w0 = Wu1[(i+0)*HD+j], w1 = Wu1[(i+1)*HD+j];
            float w2 = Wu1[(i+2)*HD+j], w3 = Wu1[(i+3)*HD+j];
#pragma unroll
            for (int k = 0; k < NBT; ++k) {
                const float4 a = *reinterpret_cast<const float4*>(&ui[k][i]);
                acc[k] += a.x*w0 + a.y*w1 + a.z*w2 + a.w*w3;
            }
        }
        {
            float w0 = Wu1[488*HD+j];
#pragma unroll
            for (int k = 0; k < NBT; ++k) acc[k] += ui[k][488] * w0;
        }
        float bb = bu1[j];
#pragma unroll
        for (int k = 0; k < NBT; ++k) u1[k][j] = silu_f(acc[k] + bb);
    }
    __syncthreads();
    if (j < HD) {
        float acc[NBT] = {0.f, 0.f, 0.f, 0.f};
        for (int i4 = 0; i4 < 60; ++i4) {
            int i = 4 * i4;
            float w0 = Wu2[(i+0)*HD+j], w1 = Wu2[(i+1)*HD+j];
            float w2 = Wu2[(i+2)*HD+j], w3 = Wu2[(i+3)*HD+j];
#pragma unroll
            for (int k = 0; k < NBT; ++k) {
                const float4 a = *reinterpret_cast<const float4*>(&u1[k][i]);
                acc[k] += a.x*w0 + a.y*w1 + a.z*w2 + a.w*w3;
            }
        }
        float bb = bu2[j];
#pragma unroll
        for (int k = 0; k < NBT; ++k) h[(size_t)(n0 + k) * HD + j] += silu_f(acc[k] + bb);
    }
}

// ---------------- readout (grid nodes only) ----------------
__global__ void output_kernel(const float* __restrict__ h,
                              const float* __restrict__ Wo1, const float* __restrict__ bo1,
                              const float* __restrict__ Wo2, const float* __restrict__ bo2,
                              float* __restrict__ out) {
    const int NBT = 4;
    __shared__ float hr[NBT][HD];
    __shared__ float o1[NBT][HD];
    int tid = threadIdx.x;
    int g0 = blockIdx.x * NBT;
    for (int idx = tid; idx < NBT * HD; idx += 256) {
        int k = idx / HD, i = idx % HD;
        hr[k][i] = h[(size_t)(NA + g0 + k) * HD + i];
    }
    __syncthreads();
    int j = tid;
    if (j < HD) {
        float acc[NBT] = {0.f, 0.f, 0.f, 0.f};
        for (int i4 = 0; i4 < 60; ++i4) {
            int i = 4 * i4;
            float w0 = Wo1[(i+0)*HD+j], w1 = Wo1[(i+1)*HD+j];
            float w2 = Wo1[(i+2)*HD+j], w3 = Wo1[(i+3)*HD+j];
#pragma unroll
            for (int k = 0; k < NBT; ++k) {
                const float4 a = *reinterpret_cast<const float4*>(&hr[k][i]);
                acc[k] += a.x*w0 + a.y*w1 + a.z*w2 + a.w*w3;
            }
        }
        float bb = bo1[j];
#pragma unroll
        for (int k = 0; k < NBT; ++k) o1[k][j] = silu_f(acc[k] + bb);
    }
    __syncthreads();
    if (tid < NBT * CD) {
        int k = tid >> 5, c = tid & 31;
        float acc = bo2[c];
        for (int i = 0; i < HD; ++i) acc += o1[k][i] * Wo2[i*CD + c];
        out[(size_t)(g0 + k) * CD + c] = acc;
    }
}

extern "C" void kernel_launch(void* const* d_in, const int* in_sizes, int n_in,
                              void* d_out, int out_size, void* d_ws, size_t ws_size,
                              hipStream_t stream) {
    (void)in_sizes; (void)n_in; (void)out_size; (void)ws_size;
    const float* pos   = (const float*)d_in[0];
    const int*   types = (const int*)d_in[1];
    const int*   batch = (const int*)d_in[2];
    const float* We    = (const float*)d_in[3];
    const float* be    = (const float*)d_in[4];
    const float* Wm1   = (const float*)d_in[5];
    const float* bm1   = (const float*)d_in[6];
    const float* Wm2   = (const float*)d_in[7];
    const float* bm2   = (const float*)d_in[8];
    const float* Wu1   = (const float*)d_in[9];
    const float* bu1   = (const float*)d_in[10];
    const float* Wu2   = (const float*)d_in[11];
    const float* bu2   = (const float*)d_in[12];
    const float* Wo1   = (const float*)d_in[13];
    const float* bo1   = (const float*)d_in[14];
    const float* Wo2   = (const float*)d_in[15];
    const float* bo2   = (const float*)d_in[16];
    float* out = (float*)d_out;

    char* ws = (char*)d_ws;
    size_t off = 0;
    auto take = [&](size_t bytes) -> char* {
        char* p = ws + off;
        off = (off + bytes + 255) & ~(size_t)255;
        return p;
    };
    int*   nbr   = (int*)take((size_t)EAE * 4);
    int*   nbg   = (int*)take((size_t)EGE * 4);
    float* ea    = (float*)take((size_t)ET * 9 * 4);
    float* emask = (float*)take((size_t)ET * 4);
    float* attr  = (float*)take((size_t)NN * 9 * 4);
    float* h     = (float*)take((size_t)NN * HD * 4);
    float* agg   = (float*)take((size_t)NN * HD * 4);

    knn_atoms_kernel<<<NA/256, 256, 0, stream>>>(pos, batch, nbr);
    knn_grid_kernel<<<NG/256, 256, 0, stream>>>(pos, batch, nbg);
    edge_kernel<<<ET/256, 256, 0, stream>>>(pos, nbr, nbg, ea, emask);
    node_attr_kernel<<<NN/256, 256, 0, stream>>>(ea, emask, attr);
    encoder_kernel<<<(NN*HD)/256, 256, 0, stream>>>(types, attr, We, be, h);

    for (int l = 0; l < 2; ++l) {
        const float* wm1 = Wm1 + (size_t)l * DIN * HD;
        const float* bb1 = bm1 + l * HD;
        const float* wm2 = Wm2 + (size_t)l * HD * HD;
        const float* bb2 = bm2 + l * HD;
        msg_kernel<KAK><<<NA, 256, 0, stream>>>(h, nbr, ea, emask, wm1, bb1, wm2, bb2, agg, 0, 0);
        msg_kernel<KGK><<<NG, 256, 0, stream>>>(h, nbg, ea, emask, wm1, bb1, wm2, bb2, agg, NA, EAE);
        update_kernel<<<NN/4, 256, 0, stream>>>(h, agg, attr,
                                                Wu1 + (size_t)l * DIN * HD, bu1 + l * HD,
                                                Wu2 + (size_t)l * HD * HD, bu2 + l * HD);
    }
    output_kernel<<<NG/4, 256, 0, stream>>>(h, Wo1, bo1, Wo2, bo2, out);
}

// Round 3
// 1137.717 us; speedup vs baseline: 2.7695x; 2.7695x over previous
//
#include <hip/hip_runtime.h>
#include <math.h>

#define NA   1024
#define NGRID 4096
#define NB   2
#define NG   (NB*NGRID)   // 8192
#define NN   (NA+NG)      // 9216
#define KAK  8
#define KGK  24
#define EAE  (NA*KAK)     // 8192
#define EGE  (NG*KGK)     // 196608
#define ET   (EAE+EGE)    // 204800
#define HD   240
#define TT   16
#define DIN  489
#define CD   32
#define CUTF 8.0f

typedef __attribute__((ext_vector_type(8))) short short8;
typedef __attribute__((ext_vector_type(4))) short short4v;
typedef __attribute__((ext_vector_type(4))) float f32x4;

__device__ __forceinline__ float silu_f(float x) {
    return x / (1.0f + __expf(-x));
}
__device__ __forceinline__ short f2bf(float x) {  // RNE f32->bf16
    unsigned u = __float_as_uint(x);
    unsigned r = (u + 0x7FFFu + ((u >> 16) & 1u)) >> 16;
    return (short)r;
}

// ---------------- kNN: atoms (K=8) ----------------
__global__ void knn_atoms_kernel(const float* __restrict__ pos, const int* __restrict__ batch,
                                 int* __restrict__ nbr) {
    __shared__ float sx[NA], sy[NA], sz[NA];
    __shared__ int   sb[NA];
    int tid = threadIdx.x;
    for (int j = tid; j < NA; j += blockDim.x) {
        sx[j] = pos[j*3+0]; sy[j] = pos[j*3+1]; sz[j] = pos[j*3+2]; sb[j] = batch[j];
    }
    __syncthreads();
    int i = blockIdx.x * blockDim.x + tid;
    float px = sx[i], py = sy[i], pz = sz[i];
    int b = sb[i];
    float bd[KAK]; int bi[KAK];
#pragma unroll
    for (int k = 0; k < KAK; ++k) { bd[k] = 3e38f; bi[k] = -1; }
    for (int j = 0; j < NA; ++j) {
        if (j == i || sb[j] != b) continue;
        float dx = px - sx[j], dy = py - sy[j], dz = pz - sz[j];
        float d2 = __fadd_rn(__fadd_rn(__fmul_rn(dx,dx), __fmul_rn(dy,dy)), __fmul_rn(dz,dz));
        if (d2 < bd[KAK-1]) {
            float d = d2; int id = j;
#pragma unroll
            for (int p = 0; p < KAK; ++p) {
                bool lt = d < bd[p];
                float td = bd[p]; int ti = bi[p];
                bd[p] = lt ? d : td; bi[p] = lt ? id : ti;
                d = lt ? td : d;   id = lt ? ti : id;
            }
        }
    }
#pragma unroll
    for (int k = 0; k < KAK; ++k) nbr[i*KAK+k] = bi[k];
}

// ---------------- kNN: grid (K=24) ----------------
__global__ void knn_grid_kernel(const float* __restrict__ pos, const int* __restrict__ batch,
                                int* __restrict__ nbg) {
    __shared__ float sx[NA], sy[NA], sz[NA];
    __shared__ int   sb[NA];
    int tid = threadIdx.x;
    for (int j = tid; j < NA; j += blockDim.x) {
        sx[j] = pos[j*3+0]; sy[j] = pos[j*3+1]; sz[j] = pos[j*3+2]; sb[j] = batch[j];
    }
    __syncthreads();
    int g = blockIdx.x * blockDim.x + tid;  // 0..8191
    int b  = g / NGRID;
    int gi = g % NGRID;
    int ix = gi >> 8, iy = (gi >> 4) & 15, iz = gi & 15;
    float px = ((float)ix - 7.5f) * 1.5f;
    float py = ((float)iy - 7.5f) * 1.5f;
    float pz = ((float)iz - 7.5f) * 1.5f;
    float bd[KGK]; int bi[KGK];
#pragma unroll
    for (int k = 0; k < KGK; ++k) { bd[k] = 3e38f; bi[k] = -1; }
    for (int j = 0; j < NA; ++j) {
        if (sb[j] != b) continue;
        float dx = px - sx[j], dy = py - sy[j], dz = pz - sz[j];
        float d2 = __fadd_rn(__fadd_rn(__fmul_rn(dx,dx), __fmul_rn(dy,dy)), __fmul_rn(dz,dz));
        if (d2 < bd[KGK-1]) {
            float d = d2; int id = j;
#pragma unroll
            for (int p = 0; p < KGK; ++p) {
                bool lt = d < bd[p];
                float td = bd[p]; int ti = bi[p];
                bd[p] = lt ? d : td; bi[p] = lt ? id : ti;
                d = lt ? td : d;   id = lt ? ti : id;
            }
        }
    }
#pragma unroll
    for (int k = 0; k < KGK; ++k) nbg[g*KGK+k] = bi[k];
}

// ---------------- edge features (sph * mask) ----------------
__global__ void edge_kernel(const float* __restrict__ pos, const int* __restrict__ nbr,
                            const int* __restrict__ nbg, float* __restrict__ ea,
                            float* __restrict__ emask) {
    int e = blockIdx.x * blockDim.x + threadIdx.x;
    if (e >= ET) return;
    int src; float dpx, dpy, dpz;
    if (e < EAE) {
        int d = e >> 3;
        src = nbr[e];
        dpx = pos[d*3]; dpy = pos[d*3+1]; dpz = pos[d*3+2];
    } else {
        int eg = e - EAE;
        src = nbg[eg];
        int gg = eg / KGK;
        int gi = gg % NGRID;
        int ix = gi >> 8, iy = (gi >> 4) & 15, iz = gi & 15;
        dpx = ((float)ix - 7.5f) * 1.5f;
        dpy = ((float)iy - 7.5f) * 1.5f;
        dpz = ((float)iz - 7.5f) * 1.5f;
    }
    float rx = pos[src*3] - dpx, ry = pos[src*3+1] - dpy, rz = pos[src*3+2] - dpz;
    float dist = sqrtf(rx*rx + ry*ry + rz*rz);
    float mask = (dist <= CUTF) ? 1.0f : 0.0f;
    float inv = 1.0f / fmaxf(dist, 1e-9f);
    float x = rx * inv, y = ry * inv, z = rz * inv;
    float s0 = 0.28209479177387814f;
    float s1 = 0.4886025119029199f * y;
    float s2 = 0.4886025119029199f * z;
    float s3 = 0.4886025119029199f * x;
    float s4 = 1.0925484305920792f * x * y;
    float s5 = 1.0925484305920792f * y * z;
    float s6 = 0.31539156525252005f * (3.0f * z * z - 1.0f);
    float s7 = 1.0925484305920792f * z * x;
    float s8 = 0.5462742152960396f * (x * x - y * y);
    float* o = &ea[(size_t)e * 9];
    o[0] = s0 * mask; o[1] = s1 * mask; o[2] = s2 * mask; o[3] = s3 * mask;
    o[4] = s4 * mask; o[5] = s5 * mask; o[6] = s6 * mask; o[7] = s7 * mask; o[8] = s8 * mask;
    emask[e] = mask;
}

// ---------------- node_attr (segment mean of ea) ----------------
__global__ void node_attr_kernel(const float* __restrict__ ea, const float* __restrict__ emask,
                                 float* __restrict__ attr) {
    int n = blockIdx.x * blockDim.x + threadIdx.x;
    if (n >= NN) return;
    int K, e0;
    if (n < NA) { K = KAK; e0 = n * KAK; }
    else        { K = KGK; e0 = EAE + (n - NA) * KGK; }
    float s[9];
#pragma unroll
    for (int a = 0; a < 9; ++a) s[a] = 0.f;
    float cnt = 0.f;
    for (int k = 0; k < K; ++k) {
        cnt += emask[e0 + k];
        const float* p = &ea[(size_t)(e0 + k) * 9];
#pragma unroll
        for (int a = 0; a < 9; ++a) s[a] += p[a];
    }
    float invc = 1.0f / fmaxf(cnt, 1.0f);
    attr[n*9+0] = 1.0f;
#pragma unroll
    for (int a = 1; a < 9; ++a) attr[n*9+a] = s[a] * invc;
}

// ---------------- encoder: h = silu([feat|attr] @ We + be) ----------------
__global__ void encoder_kernel(const int* __restrict__ types, const float* __restrict__ attr,
                               const float* __restrict__ We, const float* __restrict__ be,
                               float* __restrict__ h) {
    int idx = blockIdx.x * blockDim.x + threadIdx.x;  // n*HD + j
    int n = idx / HD, j = idx % HD;
    float acc = be[j];
    if (n < NA) acc += We[types[n] * HD + j];
#pragma unroll
    for (int a = 0; a < 9; ++a) acc += attr[n*9+a] * We[(TT + a) * HD + j];
    h[idx] = silu_f(acc);
}

// ---------------- Wm2 -> bf16, transposed & K-padded: wm2t[l][col][k(256)] ----------------
__global__ void convert_wm2_kernel(const float* __restrict__ Wm2, short* __restrict__ wm2t) {
    int idx = blockIdx.x * blockDim.x + threadIdx.x;  // < 2*240*256
    int l = idx / (240*256);
    int rem = idx % (240*256);
    int col = rem / 256, k = rem % 256;
    short v = 0;
    if (k < 240) v = f2bf(Wm2[(size_t)l*57600 + k*240 + col]);
    wm2t[idx] = v;
}

// ---------------- per-node partial GEMMs: Zd = h@Wm1[240:480]+bm1 ; Zs = h@Wm1[0:240] (atoms only) ----------------
__global__ void node_z_kernel(const float* __restrict__ h, const float* __restrict__ Wm1,
                              const float* __restrict__ bm1,
                              float* __restrict__ Zs, float* __restrict__ Zd) {
    const int NBT = 8;
    __shared__ float hs[NBT*HD];
    int tid = threadIdx.x;
    int n0 = blockIdx.x * NBT;
    for (int idx = tid; idx < NBT*HD; idx += 256)
        hs[idx] = h[(size_t)n0*HD + idx];
    __syncthreads();
    int j = tid;
    if (j >= HD) return;
    if (n0 < NA) {
        float zd[NBT], zs[NBT];
        float b = bm1[j];
#pragma unroll
        for (int k = 0; k < NBT; ++k) { zd[k] = b; zs[k] = 0.f; }
        for (int i = 0; i < HD; ++i) {
            float wd = Wm1[(240 + i)*HD + j];
            float ws = Wm1[i*HD + j];
#pragma unroll
            for (int k = 0; k < NBT; ++k) {
                float hv = hs[k*HD + i];
                zd[k] += hv * wd;
                zs[k] += hv * ws;
            }
        }
#pragma unroll
        for (int k = 0; k < NBT; ++k) {
            Zd[(size_t)(n0 + k)*HD + j] = zd[k];
            Zs[(size_t)(n0 + k)*HD + j] = zs[k];
        }
    } else {
        float zd[NBT];
        float b = bm1[j];
#pragma unroll
        for (int k = 0; k < NBT; ++k) zd[k] = b;
        for (int i = 0; i < HD; ++i) {
            float wd = Wm1[(240 + i)*HD + j];
#pragma unroll
            for (int k = 0; k < NBT; ++k) zd[k] += hs[k*HD + i] * wd;
        }
#pragma unroll
        for (int k = 0; k < NBT; ++k) Zd[(size_t)(n0 + k)*HD + j] = zd[k];
    }
}

// ---------------- fused message MLP: assemble m1 (bf16) -> MFMA m1@Wm2 -> silu*mask -> per-node sum ----------------
// KE edges per node, NPB nodes per block; ROWS = KE*NPB (48 grid / 64 atoms); 192 threads = 3 waves.
// Wave w computes all M-tiles x N-columns [80w, 80w+80).
template <int KE, int NPB>
__global__ __launch_bounds__(192) void msg_mfma_kernel(
        const float* __restrict__ Zs, const float* __restrict__ Zd,
        const int* __restrict__ nbrList, const float* __restrict__ ea,
        const float* __restrict__ emask, const float* __restrict__ Wea,
        const short* __restrict__ wm2t, const float* __restrict__ bm2,
        float* __restrict__ agg, int dstBase, int edgeBase) {
    constexpr int ROWS = KE * NPB;     // 48 or 64
    constexpr int MT = ROWS / 16;      // 3 or 4
    __shared__ __align__(16) short Abuf[ROWS * 264];  // m1 tile, K padded to 256 (+8 bank pad)
    __shared__ __align__(16) float mkbuf[ROWS];

    int tid = threadIdx.x;
    int b = blockIdx.x;
    int e0 = edgeBase + b * ROWS;

    if (tid < ROWS) mkbuf[tid] = emask[e0 + tid];
    // zero K-pad columns 240..263
    for (int idx = tid; idx < ROWS * 24; idx += 192) {
        int r = idx / 24;
        Abuf[r * 264 + 240 + (idx % 24)] = 0;
    }
    // assemble m1 rows: silu(Zs[src] + Zd[dst] + ea@Wea) -> bf16
    for (int idx = tid; idx < ROWS * 60; idx += 192) {
        int row = idx / 60;
        int j = (idx % 60) * 4;
        int srcn = nbrList[b * ROWS + row];
        int dstn = dstBase + b * NPB + row / KE;
        const float4 zs = *(const float4*)(Zs + (size_t)srcn * HD + j);
        const float4 zd = *(const float4*)(Zd + (size_t)dstn * HD + j);
        float s0 = zs.x + zd.x, s1 = zs.y + zd.y, s2 = zs.z + zd.z, s3 = zs.w + zd.w;
        const float* ep = ea + (size_t)(e0 + row) * 9;
#pragma unroll
        for (int a = 0; a < 9; ++a) {
            float ev = ep[a];
            const float4 w = *(const float4*)(Wea + a * HD + j);
            s0 += ev * w.x; s1 += ev * w.y; s2 += ev * w.z; s3 += ev * w.w;
        }
        short4v o;
        o.x = f2bf(silu_f(s0)); o.y = f2bf(silu_f(s1));
        o.z = f2bf(silu_f(s2)); o.w = f2bf(silu_f(s3));
        *(short4v*)&Abuf[row * 264 + j] = o;
    }
    __syncthreads();

    int w = tid / 64, lane = tid % 64;
    int lg = lane >> 4, lc = lane & 15;
    int wcol0 = w * 80;

    f32x4 acc[MT][5];
#pragma unroll
    for (int mt = 0; mt < MT; ++mt)
#pragma unroll
        for (int nt = 0; nt < 5; ++nt) acc[mt][nt] = (f32x4){0.f, 0.f, 0.f, 0.f};

#pragma unroll
    for (int kc = 0; kc < 8; ++kc) {
        short8 af[MT];
#pragma unroll
        for (int mt = 0; mt < MT; ++mt)
            af[mt] = *(const short8*)&Abuf[(mt * 16 + lc) * 264 + kc * 32 + lg * 8];
#pragma unroll
        for (int nt = 0; nt < 5; ++nt) {
            const short8 bf = *(const short8*)(wm2t + (size_t)(wcol0 + nt * 16 + lc) * 256 + kc * 32 + lg * 8);
#pragma unroll
            for (int mt = 0; mt < MT; ++mt)
                acc[mt][nt] = __builtin_amdgcn_mfma_f32_16x16x32_bf16(af[mt], bf, acc[mt][nt], 0, 0, 0);
        }
    }

    // epilogue: silu(acc + bm2)*mask, reduce over each node's KE rows, store agg
#pragma unroll
    for (int nt = 0; nt < 5; ++nt) {
        int ncol = wcol0 + nt * 16 + lc;
        float bias = bm2[ncol];
        float p[MT];
#pragma unroll
        for (int mt = 0; mt < MT; ++mt) {
            const float4 mkv = *(const float4*)&mkbuf[mt * 16 + lg * 4];
            float t0 = silu_f(acc[mt][nt].x + bias) * mkv.x;
            float t1 = silu_f(acc[mt][nt].y + bias) * mkv.y;
            float t2 = silu_f(acc[mt][nt].z + bias) * mkv.z;
            float t3 = silu_f(acc[mt][nt].w + bias) * mkv.w;
            p[mt] = (t0 + t1) + (t2 + t3);
        }
        if (KE == 24) {
            // node0 = rows 0..23 (mt0 all + mt1 lanegroups 0,1); node1 = rows 24..47
            float v0 = p[0] + ((lg < 2) ? p[1] : 0.f);
            float v1 = ((lg >= 2) ? p[1] : 0.f) + p[2];
            v0 += __shfl_xor(v0, 16); v0 += __shfl_xor(v0, 32);
            v1 += __shfl_xor(v1, 16); v1 += __shfl_xor(v1, 32);
            if (lane < 16)      agg[(size_t)(dstBase + b * 2 + 0) * HD + ncol] = v0;
            else if (lane < 32) agg[(size_t)(dstBase + b * 2 + 1) * HD + ncol] = v1;
        } else {
            // KE==8: each m-tile = 2 nodes (rows 0..7 -> lanegroups 0,1; rows 8..15 -> 2,3)
#pragma unroll
            for (int mt = 0; mt < MT; ++mt) {
                float v = p[mt];
                v += __shfl_xor(v, 16);
                if (lane < 16)
                    agg[(size_t)(dstBase + b * (2 * MT) + 2 * mt + 0) * HD + ncol] = v;
                else if (lane >= 32 && lane < 48)
                    agg[(size_t)(dstBase + b * (2 * MT) + 2 * mt + 1) * HD + ncol] = v;
            }
        }
    }
}

// ---------------- node update: h += MLP([h|agg|attr]) ----------------
__global__ void update_kernel(float* __restrict__ h, const float* __restrict__ agg,
                              const float* __restrict__ attr,
                              const float* __restrict__ Wu1, const float* __restrict__ bu1,
                              const float* __restrict__ Wu2, const float* __restrict__ bu2) {
    const int NBT = 4;
    __shared__ float ui[NBT][492];
    __shared__ float u1[NBT][HD];
    int tid = threadIdx.x;
    int n0 = blockIdx.x * NBT;
    for (int idx = tid; idx < NBT * 492; idx += 256) {
        int k = idx / 492, i = idx % 492;
        int n = n0 + k;
        float v;
        if (i < 240)      v = h[(size_t)n * HD + i];
        else if (i < 480) v = agg[(size_t)n * HD + (i - 240)];
        else if (i < 489) v = attr[n*9 + (i - 480)];
        else              v = 0.f;
        ui[k][i] = v;
    }
    __syncthreads();
    int j = tid;
    if (j < HD) {
        float acc[NBT] = {0.f, 0.f, 0.f, 0.f};
        for (int i4 = 0; i4 < 122; ++i4) {
            int i = 4 * i4;
            float w0 = Wu1[(i+0)*HD+j], w1 = Wu1[(i+1)*HD+j];
            float w2 = Wu1[(i+2)*HD+j], w3 = Wu1[(i+3)*HD+j];
#pragma unroll
            for (int k = 0; k < NBT; ++k) {
                const float4 a = *reinterpret_cast<const float4*>(&ui[k][i]);
                acc[k] += a.x*w0 + a.y*w1 + a.z*w2 + a.w*w3;
            }
        }
        {
            float w0 = Wu1[488*HD+j];
#pragma unroll
            for (int k = 0; k < NBT; ++k) acc[k] += ui[k][488] * w0;
        }
        float bb = bu1[j];
#pragma unroll
        for (int k = 0; k < NBT; ++k) u1[k][j] = silu_f(acc[k] + bb);
    }
    __syncthreads();
    if (j < HD) {
        float acc[NBT] = {0.f, 0.f, 0.f, 0.f};
        for (int i4 = 0; i4 < 60; ++i4) {
            int i = 4 * i4;
            float w0 = Wu2[(i+0)*HD+j], w1 = Wu2[(i+1)*HD+j];
            float w2 = Wu2[(i+2)*HD+j], w3 = Wu2[(i+3)*HD+j];
#pragma unroll
            for (int k = 0; k < NBT; ++k) {
                const float4 a = *reinterpret_cast<const float4*>(&u1[k][i]);
                acc[k] += a.x*w0 + a.y*w1 + a.z*w2 + a.w*w3;
            }
        }
        float bb = bu2[j];
#pragma unroll
        for (int k = 0; k < NBT; ++k) h[(size_t)(n0 + k) * HD + j] += silu_f(acc[k] + bb);
    }
}

// ---------------- readout (grid nodes only) ----------------
__global__ void output_kernel(const float* __restrict__ h,
                              const float* __restrict__ Wo1, const float* __restrict__ bo1,
                              const float* __restrict__ Wo2, const float* __restrict__ bo2,
                              float* __restrict__ out) {
    const int NBT = 4;
    __shared__ float hr[NBT][HD];
    __shared__ float o1[NBT][HD];
    int tid = threadIdx.x;
    int g0 = blockIdx.x * NBT;
    for (int idx = tid; idx < NBT * HD; idx += 256) {
        int k = idx / HD, i = idx % HD;
        hr[k][i] = h[(size_t)(NA + g0 + k) * HD + i];
    }
    __syncthreads();
    int j = tid;
    if (j < HD) {
        float acc[NBT] = {0.f, 0.f, 0.f, 0.f};
        for (int i4 = 0; i4 < 60; ++i4) {
            int i = 4 * i4;
            float w0 = Wo1[(i+0)*HD+j], w1 = Wo1[(i+1)*HD+j];
            float w2 = Wo1[(i+2)*HD+j], w3 = Wo1[(i+3)*HD+j];
#pragma unroll
            for (int k = 0; k < NBT; ++k) {
                const float4 a = *reinterpret_cast<const float4*>(&hr[k][i]);
                acc[k] += a.x*w0 + a.y*w1 + a.z*w2 + a.w*w3;
            }
        }
        float bb = bo1[j];
#pragma unroll
        for (int k = 0; k < NBT; ++k) o1[k][j] = silu_f(acc[k] + bb);
    }
    __syncthreads();
    if (tid < NBT * CD) {
        int k = tid >> 5, c = tid & 31;
        float acc = bo2[c];
        for (int i = 0; i < HD; ++i) acc += o1[k][i] * Wo2[i*CD + c];
        out[(size_t)(g0 + k) * CD + c] = acc;
    }
}

extern "C" void kernel_launch(void* const* d_in, const int* in_sizes, int n_in,
                              void* d_out, int out_size, void* d_ws, size_t ws_size,
                              hipStream_t stream) {
    (void)in_sizes; (void)n_in; (void)out_size; (void)ws_size;
    const float* pos   = (const float*)d_in[0];
    const int*   types = (const int*)d_in[1];
    const int*   batch = (const int*)d_in[2];
    const float* We    = (const float*)d_in[3];
    const float* be    = (const float*)d_in[4];
    const float* Wm1   = (const float*)d_in[5];
    const float* bm1   = (const float*)d_in[6];
    const float* Wm2   = (const float*)d_in[7];
    const float* bm2   = (const float*)d_in[8];
    const float* Wu1   = (const float*)d_in[9];
    const float* bu1   = (const float*)d_in[10];
    const float* Wu2   = (const float*)d_in[11];
    const float* bu2   = (const float*)d_in[12];
    const float* Wo1   = (const float*)d_in[13];
    const float* bo1   = (const float*)d_in[14];
    const float* Wo2   = (const float*)d_in[15];
    const float* bo2   = (const float*)d_in[16];
    float* out = (float*)d_out;

    char* ws = (char*)d_ws;
    size_t off = 0;
    auto take = [&](size_t bytes) -> char* {
        char* p = ws + off;
        off = (off + bytes + 255) & ~(size_t)255;
        return p;
    };
    int*   nbr   = (int*)take((size_t)EAE * 4);
    int*   nbg   = (int*)take((size_t)EGE * 4);
    float* ea    = (float*)take((size_t)ET * 9 * 4);
    float* emask = (float*)take((size_t)ET * 4);
    float* attr  = (float*)take((size_t)NN * 9 * 4);
    float* h     = (float*)take((size_t)NN * HD * 4);
    float* agg   = (float*)take((size_t)NN * HD * 4);
    float* zs    = (float*)take((size_t)NA * HD * 4);
    float* zd    = (float*)take((size_t)NN * HD * 4);
    short* wm2t  = (short*)take((size_t)2 * 240 * 256 * 2);

    knn_atoms_kernel<<<NA/256, 256, 0, stream>>>(pos, batch, nbr);
    knn_grid_kernel<<<NG/256, 256, 0, stream>>>(pos, batch, nbg);
    edge_kernel<<<ET/256, 256, 0, stream>>>(pos, nbr, nbg, ea, emask);
    node_attr_kernel<<<NN/256, 256, 0, stream>>>(ea, emask, attr);
    encoder_kernel<<<(NN*HD)/256, 256, 0, stream>>>(types, attr, We, be, h);
    convert_wm2_kernel<<<(2*240*256)/256, 256, 0, stream>>>(Wm2, wm2t);

    for (int l = 0; l < 2; ++l) {
        const float* wm1 = Wm1 + (size_t)l * DIN * HD;
        const float* bb1 = bm1 + l * HD;
        const float* wea = wm1 + (size_t)480 * HD;
        const short* w2t = wm2t + (size_t)l * 240 * 256;
        const float* bb2 = bm2 + l * HD;
        node_z_kernel<<<NN/8, 256, 0, stream>>>(h, wm1, bb1, zs, zd);
        msg_mfma_kernel<KAK, 8><<<NA*KAK/64, 192, 0, stream>>>(
            zs, zd, nbr, ea, emask, wea, w2t, bb2, agg, 0, 0);
        msg_mfma_kernel<KGK, 2><<<NG*KGK/48, 192, 0, stream>>>(
            zs, zd, nbg, ea, emask, wea, w2t, bb2, agg, NA, EAE);
        update_kernel<<<NN/4, 256, 0, stream>>>(h, agg, attr,
                                                Wu1 + (size_t)l * DIN * HD, bu1 + l * HD,
                                                Wu2 + (size_t)l * HD * HD, bu2 + l * HD);
    }
    output_kernel<<<NG/4, 256, 0, stream>>>(h, Wo1, bo1, Wo2, bo2, out);
}

// Round 4
// 1055.305 us; speedup vs baseline: 2.9858x; 1.0781x over previous
//
#include <hip/hip_runtime.h>
#include <math.h>

#define NA   1024
#define NGRID 4096
#define NB   2
#define NG   (NB*NGRID)   // 8192
#define NN   (NA+NG)      // 9216
#define KAK  8
#define KGK  24
#define EAE  (NA*KAK)     // 8192
#define EGE  (NG*KGK)     // 196608
#define ET   (EAE+EGE)    // 204800
#define HD   240
#define TT   16
#define DIN  489
#define CD   32
#define CUTF 8.0f

typedef __attribute__((ext_vector_type(8))) short short8;
typedef __attribute__((ext_vector_type(4))) short short4v;
typedef __attribute__((ext_vector_type(4))) float f32x4;

__device__ __forceinline__ float silu_f(float x) {
    return x / (1.0f + __expf(-x));
}
__device__ __forceinline__ short f2bf(float x) {  // RNE f32->bf16
    unsigned u = __float_as_uint(x);
    unsigned r = (u + 0x7FFFu + ((u >> 16) & 1u)) >> 16;
    return (short)r;
}

// ---------------- kNN: atoms (K=8), 8 threads per query ----------------
__global__ __launch_bounds__(256) void knn_atoms_kernel(const float* __restrict__ pos,
                                                        const int* __restrict__ batch,
                                                        int* __restrict__ nbr) {
    const int P = 8, QB = 32, CH = NA / P;  // 128 candidates per thread
    __shared__ float sx[NA], sy[NA], sz[NA];
    __shared__ int   sb[NA];
    __shared__ float pd[QB * P * KAK];
    __shared__ int   pi[QB * P * KAK];
    int tid = threadIdx.x;
    for (int j = tid; j < NA; j += 256) {
        sx[j] = pos[j*3+0]; sy[j] = pos[j*3+1]; sz[j] = pos[j*3+2]; sb[j] = batch[j];
    }
    __syncthreads();
    int q = tid / P, t = tid % P;
    int i = blockIdx.x * QB + q;
    float px = sx[i], py = sy[i], pz = sz[i];
    int b = sb[i];
    float bd[KAK]; int bi[KAK];
#pragma unroll
    for (int k = 0; k < KAK; ++k) { bd[k] = 3e38f; bi[k] = -1; }
    for (int j = t * CH; j < (t + 1) * CH; ++j) {
        if (j == i || sb[j] != b) continue;
        float dx = px - sx[j], dy = py - sy[j], dz = pz - sz[j];
        float d2 = __fadd_rn(__fadd_rn(__fmul_rn(dx,dx), __fmul_rn(dy,dy)), __fmul_rn(dz,dz));
        if (d2 < bd[KAK-1]) {
            float d = d2; int id = j;
#pragma unroll
            for (int p = 0; p < KAK; ++p) {
                bool lt = d < bd[p];
                float td = bd[p]; int ti = bi[p];
                bd[p] = lt ? d : td; bi[p] = lt ? id : ti;
                d = lt ? td : d;   id = lt ? ti : id;
            }
        }
    }
    int base = (q * P + t) * KAK;
#pragma unroll
    for (int k = 0; k < KAK; ++k) { pd[base+k] = bd[k]; pi[base+k] = bi[k]; }
    __syncthreads();
    if (t == 0) {
        float fd[KAK]; int fi[KAK];
#pragma unroll
        for (int k = 0; k < KAK; ++k) { fd[k] = 3e38f; fi[k] = -1; }
        for (int tt = 0; tt < P; ++tt) {
            int bb = (q * P + tt) * KAK;
            for (int k = 0; k < KAK; ++k) {
                float d = pd[bb+k];
                if (!(d < fd[KAK-1])) break;  // sorted partial list -> rest fail too
                int id = pi[bb+k];
#pragma unroll
                for (int p = 0; p < KAK; ++p) {
                    bool lt = d < fd[p];
                    float td = fd[p]; int ti = fi[p];
                    fd[p] = lt ? d : td; fi[p] = lt ? id : ti;
                    d = lt ? td : d;   id = lt ? ti : id;
                }
            }
        }
#pragma unroll
        for (int k = 0; k < KAK; ++k) nbr[i*KAK+k] = fi[k];
    }
}

// ---------------- kNN: grid (K=24), 4 threads per query ----------------
__global__ __launch_bounds__(256) void knn_grid_kernel(const float* __restrict__ pos,
                                                       const int* __restrict__ batch,
                                                       int* __restrict__ nbg) {
    const int P = 4, QB = 64, CH = NA / P;  // 256 candidates per thread
    __shared__ float sx[NA], sy[NA], sz[NA];
    __shared__ int   sb[NA];
    __shared__ float pd[QB * P * KGK];
    __shared__ int   pi[QB * P * KGK];
    int tid = threadIdx.x;
    for (int j = tid; j < NA; j += 256) {
        sx[j] = pos[j*3+0]; sy[j] = pos[j*3+1]; sz[j] = pos[j*3+2]; sb[j] = batch[j];
    }
    __syncthreads();
    int q = tid / P, t = tid % P;
    int g = blockIdx.x * QB + q;       // 0..8191
    int b  = g / NGRID;
    int gi = g % NGRID;
    int ix = gi >> 8, iy = (gi >> 4) & 15, iz = gi & 15;
    float px = ((float)ix - 7.5f) * 1.5f;
    float py = ((float)iy - 7.5f) * 1.5f;
    float pz = ((float)iz - 7.5f) * 1.5f;
    float bd[KGK]; int bi[KGK];
#pragma unroll
    for (int k = 0; k < KGK; ++k) { bd[k] = 3e38f; bi[k] = -1; }
    for (int j = t * CH; j < (t + 1) * CH; ++j) {
        if (sb[j] != b) continue;
        float dx = px - sx[j], dy = py - sy[j], dz = pz - sz[j];
        float d2 = __fadd_rn(__fadd_rn(__fmul_rn(dx,dx), __fmul_rn(dy,dy)), __fmul_rn(dz,dz));
        if (d2 < bd[KGK-1]) {
            float d = d2; int id = j;
#pragma unroll
            for (int p = 0; p < KGK; ++p) {
                bool lt = d < bd[p];
                float td = bd[p]; int ti = bi[p];
                bd[p] = lt ? d : td; bi[p] = lt ? id : ti;
                d = lt ? td : d;   id = lt ? ti : id;
            }
        }
    }
    int base = (q * P + t) * KGK;
#pragma unroll
    for (int k = 0; k < KGK; ++k) { pd[base+k] = bd[k]; pi[base+k] = bi[k]; }
    __syncthreads();
    if (t == 0) {
        float fd[KGK]; int fi[KGK];
#pragma unroll
        for (int k = 0; k < KGK; ++k) { fd[k] = 3e38f; fi[k] = -1; }
        for (int tt = 0; tt < P; ++tt) {
            int bb = (q * P + tt) * KGK;
            for (int k = 0; k < KGK; ++k) {
                float d = pd[bb+k];
                if (!(d < fd[KGK-1])) break;
                int id = pi[bb+k];
#pragma unroll
                for (int p = 0; p < KGK; ++p) {
                    bool lt = d < fd[p];
                    float td = fd[p]; int ti = fi[p];
                    fd[p] = lt ? d : td; fi[p] = lt ? id : ti;
                    d = lt ? td : d;   id = lt ? ti : id;
                }
            }
        }
#pragma unroll
        for (int k = 0; k < KGK; ++k) nbg[g*KGK+k] = fi[k];
    }
}

// ---------------- edge features (sph * mask) ----------------
__global__ void edge_kernel(const float* __restrict__ pos, const int* __restrict__ nbr,
                            const int* __restrict__ nbg, float* __restrict__ ea,
                            float* __restrict__ emask) {
    int e = blockIdx.x * blockDim.x + threadIdx.x;
    if (e >= ET) return;
    int src; float dpx, dpy, dpz;
    if (e < EAE) {
        int d = e >> 3;
        src = nbr[e];
        dpx = pos[d*3]; dpy = pos[d*3+1]; dpz = pos[d*3+2];
    } else {
        int eg = e - EAE;
        src = nbg[eg];
        int gg = eg / KGK;
        int gi = gg % NGRID;
        int ix = gi >> 8, iy = (gi >> 4) & 15, iz = gi & 15;
        dpx = ((float)ix - 7.5f) * 1.5f;
        dpy = ((float)iy - 7.5f) * 1.5f;
        dpz = ((float)iz - 7.5f) * 1.5f;
    }
    float rx = pos[src*3] - dpx, ry = pos[src*3+1] - dpy, rz = pos[src*3+2] - dpz;
    float dist = sqrtf(rx*rx + ry*ry + rz*rz);
    float mask = (dist <= CUTF) ? 1.0f : 0.0f;
    float inv = 1.0f / fmaxf(dist, 1e-9f);
    float x = rx * inv, y = ry * inv, z = rz * inv;
    float s0 = 0.28209479177387814f;
    float s1 = 0.4886025119029199f * y;
    float s2 = 0.4886025119029199f * z;
    float s3 = 0.4886025119029199f * x;
    float s4 = 1.0925484305920792f * x * y;
    float s5 = 1.0925484305920792f * y * z;
    float s6 = 0.31539156525252005f * (3.0f * z * z - 1.0f);
    float s7 = 1.0925484305920792f * z * x;
    float s8 = 0.5462742152960396f * (x * x - y * y);
    float* o = &ea[(size_t)e * 9];
    o[0] = s0 * mask; o[1] = s1 * mask; o[2] = s2 * mask; o[3] = s3 * mask;
    o[4] = s4 * mask; o[5] = s5 * mask; o[6] = s6 * mask; o[7] = s7 * mask; o[8] = s8 * mask;
    emask[e] = mask;
}

// ---------------- node_attr (segment mean of ea) ----------------
__global__ void node_attr_kernel(const float* __restrict__ ea, const float* __restrict__ emask,
                                 float* __restrict__ attr) {
    int n = blockIdx.x * blockDim.x + threadIdx.x;
    if (n >= NN) return;
    int K, e0;
    if (n < NA) { K = KAK; e0 = n * KAK; }
    else        { K = KGK; e0 = EAE + (n - NA) * KGK; }
    float s[9];
#pragma unroll
    for (int a = 0; a < 9; ++a) s[a] = 0.f;
    float cnt = 0.f;
    for (int k = 0; k < K; ++k) {
        cnt += emask[e0 + k];
        const float* p = &ea[(size_t)(e0 + k) * 9];
#pragma unroll
        for (int a = 0; a < 9; ++a) s[a] += p[a];
    }
    float invc = 1.0f / fmaxf(cnt, 1.0f);
    attr[n*9+0] = 1.0f;
#pragma unroll
    for (int a = 1; a < 9; ++a) attr[n*9+a] = s[a] * invc;
}

// ---------------- encoder: h = silu([feat|attr] @ We + be) ----------------
__global__ void encoder_kernel(const int* __restrict__ types, const float* __restrict__ attr,
                               const float* __restrict__ We, const float* __restrict__ be,
                               float* __restrict__ h) {
    int idx = blockIdx.x * blockDim.x + threadIdx.x;  // n*HD + j
    int n = idx / HD, j = idx % HD;
    float acc = be[j];
    if (n < NA) acc += We[types[n] * HD + j];
#pragma unroll
    for (int a = 0; a < 9; ++a) acc += attr[n*9+a] * We[(TT + a) * HD + j];
    h[idx] = silu_f(acc);
}

// ---------------- Wm2 -> bf16, transposed & K-padded: wm2t[l][col][k(256)] ----------------
__global__ void convert_wm2_kernel(const float* __restrict__ Wm2, short* __restrict__ wm2t) {
    int idx = blockIdx.x * blockDim.x + threadIdx.x;  // < 2*240*256
    int l = idx / (240*256);
    int rem = idx % (240*256);
    int col = rem / 256, k = rem % 256;
    short v = 0;
    if (k < 240) v = f2bf(Wm2[(size_t)l*57600 + k*240 + col]);
    wm2t[idx] = v;
}

// ---------------- per-node partial GEMMs: Zd = h@Wm1[240:480]+bm1 ; Zs = h@Wm1[0:240] (atoms only) ----------------
__global__ void node_z_kernel(const float* __restrict__ h, const float* __restrict__ Wm1,
                              const float* __restrict__ bm1,
                              float* __restrict__ Zs, float* __restrict__ Zd) {
    const int NBT = 8;
    __shared__ float hs[NBT*HD];
    int tid = threadIdx.x;
    int n0 = blockIdx.x * NBT;
    for (int idx = tid; idx < NBT*HD; idx += 256)
        hs[idx] = h[(size_t)n0*HD + idx];
    __syncthreads();
    int j = tid;
    if (j >= HD) return;
    if (n0 < NA) {
        float zd[NBT], zs[NBT];
        float b = bm1[j];
#pragma unroll
        for (int k = 0; k < NBT; ++k) { zd[k] = b; zs[k] = 0.f; }
        for (int i = 0; i < HD; ++i) {
            float wd = Wm1[(240 + i)*HD + j];
            float ws = Wm1[i*HD + j];
#pragma unroll
            for (int k = 0; k < NBT; ++k) {
                float hv = hs[k*HD + i];
                zd[k] += hv * wd;
                zs[k] += hv * ws;
            }
        }
#pragma unroll
        for (int k = 0; k < NBT; ++k) {
            Zd[(size_t)(n0 + k)*HD + j] = zd[k];
            Zs[(size_t)(n0 + k)*HD + j] = zs[k];
        }
    } else {
        float zd[NBT];
        float b = bm1[j];
#pragma unroll
        for (int k = 0; k < NBT; ++k) zd[k] = b;
        for (int i = 0; i < HD; ++i) {
            float wd = Wm1[(240 + i)*HD + j];
#pragma unroll
            for (int k = 0; k < NBT; ++k) zd[k] += hs[k*HD + i] * wd;
        }
#pragma unroll
        for (int k = 0; k < NBT; ++k) Zd[(size_t)(n0 + k)*HD + j] = zd[k];
    }
}

// ---------------- fused message MLP: assemble m1 (bf16) -> MFMA m1@Wm2 -> silu*mask -> per-node sum ----------------
template <int KE, int NPB>
__global__ __launch_bounds__(192) void msg_mfma_kernel(
        const float* __restrict__ Zs, const float* __restrict__ Zd,
        const int* __restrict__ nbrList, const float* __restrict__ ea,
        const float* __restrict__ emask, const float* __restrict__ Wea,
        const short* __restrict__ wm2t, const float* __restrict__ bm2,
        float* __restrict__ agg, int dstBase, int edgeBase) {
    constexpr int ROWS = KE * NPB;     // 48 or 64
    constexpr int MT = ROWS / 16;      // 3 or 4
    __shared__ __align__(16) short Abuf[ROWS * 264];  // m1 tile, K padded to 256 (+8 bank pad)
    __shared__ __align__(16) float mkbuf[ROWS];

    int tid = threadIdx.x;
    int b = blockIdx.x;
    int e0 = edgeBase + b * ROWS;

    if (tid < ROWS) mkbuf[tid] = emask[e0 + tid];
    for (int idx = tid; idx < ROWS * 24; idx += 192) {
        int r = idx / 24;
        Abuf[r * 264 + 240 + (idx % 24)] = 0;
    }
    for (int idx = tid; idx < ROWS * 60; idx += 192) {
        int row = idx / 60;
        int j = (idx % 60) * 4;
        int srcn = nbrList[b * ROWS + row];
        int dstn = dstBase + b * NPB + row / KE;
        const float4 zs = *(const float4*)(Zs + (size_t)srcn * HD + j);
        const float4 zd = *(const float4*)(Zd + (size_t)dstn * HD + j);
        float s0 = zs.x + zd.x, s1 = zs.y + zd.y, s2 = zs.z + zd.z, s3 = zs.w + zd.w;
        const float* ep = ea + (size_t)(e0 + row) * 9;
#pragma unroll
        for (int a = 0; a < 9; ++a) {
            float ev = ep[a];
            const float4 w = *(const float4*)(Wea + a * HD + j);
            s0 += ev * w.x; s1 += ev * w.y; s2 += ev * w.z; s3 += ev * w.w;
        }
        short4v o;
        o.x = f2bf(silu_f(s0)); o.y = f2bf(silu_f(s1));
        o.z = f2bf(silu_f(s2)); o.w = f2bf(silu_f(s3));
        *(short4v*)&Abuf[row * 264 + j] = o;
    }
    __syncthreads();

    int w = tid / 64, lane = tid % 64;
    int lg = lane >> 4, lc = lane & 15;
    int wcol0 = w * 80;

    f32x4 acc[MT][5];
#pragma unroll
    for (int mt = 0; mt < MT; ++mt)
#pragma unroll
        for (int nt = 0; nt < 5; ++nt) acc[mt][nt] = (f32x4){0.f, 0.f, 0.f, 0.f};

#pragma unroll
    for (int kc = 0; kc < 8; ++kc) {
        short8 af[MT];
#pragma unroll
        for (int mt = 0; mt < MT; ++mt)
            af[mt] = *(const short8*)&Abuf[(mt * 16 + lc) * 264 + kc * 32 + lg * 8];
#pragma unroll
        for (int nt = 0; nt < 5; ++nt) {
            const short8 bf = *(const short8*)(wm2t + (size_t)(wcol0 + nt * 16 + lc) * 256 + kc * 32 + lg * 8);
#pragma unroll
            for (int mt = 0; mt < MT; ++mt)
                acc[mt][nt] = __builtin_amdgcn_mfma_f32_16x16x32_bf16(af[mt], bf, acc[mt][nt], 0, 0, 0);
        }
    }

#pragma unroll
    for (int nt = 0; nt < 5; ++nt) {
        int ncol = wcol0 + nt * 16 + lc;
        float bias = bm2[ncol];
        float p[MT];
#pragma unroll
        for (int mt = 0; mt < MT; ++mt) {
            const float4 mkv = *(const float4*)&mkbuf[mt * 16 + lg * 4];
            float t0 = silu_f(acc[mt][nt].x + bias) * mkv.x;
            float t1 = silu_f(acc[mt][nt].y + bias) * mkv.y;
            float t2 = silu_f(acc[mt][nt].z + bias) * mkv.z;
            float t3 = silu_f(acc[mt][nt].w + bias) * mkv.w;
            p[mt] = (t0 + t1) + (t2 + t3);
        }
        if (KE == 24) {
            float v0 = p[0] + ((lg < 2) ? p[1] : 0.f);
            float v1 = ((lg >= 2) ? p[1] : 0.f) + p[2];
            v0 += __shfl_xor(v0, 16); v0 += __shfl_xor(v0, 32);
            v1 += __shfl_xor(v1, 16); v1 += __shfl_xor(v1, 32);
            if (lane < 16)      agg[(size_t)(dstBase + b * 2 + 0) * HD + ncol] = v0;
            else if (lane < 32) agg[(size_t)(dstBase + b * 2 + 1) * HD + ncol] = v1;
        } else {
#pragma unroll
            for (int mt = 0; mt < MT; ++mt) {
                float v = p[mt];
                v += __shfl_xor(v, 16);
                if (lane < 16)
                    agg[(size_t)(dstBase + b * (2 * MT) + 2 * mt + 0) * HD + ncol] = v;
                else if (lane >= 32 && lane < 48)
                    agg[(size_t)(dstBase + b * (2 * MT) + 2 * mt + 1) * HD + ncol] = v;
            }
        }
    }
}

// ---------------- node update: h += MLP([h|agg|attr]) ----------------
__global__ void update_kernel(float* __restrict__ h, const float* __restrict__ agg,
                              const float* __restrict__ attr,
                              const float* __restrict__ Wu1, const float* __restrict__ bu1,
                              const float* __restrict__ Wu2, const float* __restrict__ bu2) {
    const int NBT = 4;
    __shared__ float ui[NBT][492];
    __shared__ float u1[NBT][HD];
    int tid = threadIdx.x;
    int n0 = blockIdx.x * NBT;
    for (int idx = tid; idx < NBT * 492; idx += 256) {
        int k = idx / 492, i = idx % 492;
        int n = n0 + k;
        float v;
        if (i < 240)      v = h[(size_t)n * HD + i];
        else if (i < 480) v = agg[(size_t)n * HD + (i - 240)];
        else if (i < 489) v = attr[n*9 + (i - 480)];
        else              v = 0.f;
        ui[k][i] = v;
    }
    __syncthreads();
    int j = tid;
    if (j < HD) {
        float acc[NBT] = {0.f, 0.f, 0.f, 0.f};
        for (int i4 = 0; i4 < 122; ++i4) {
            int i = 4 * i4;
            float w0 = Wu1[(i+0)*HD+j], w1 = Wu1[(i+1)*HD+j];
            float w2 = Wu1[(i+2)*HD+j], w3 = Wu1[(i+3)*HD+j];
#pragma unroll
            for (int k = 0; k < NBT; ++k) {
                const float4 a = *reinterpret_cast<const float4*>(&ui[k][i]);
                acc[k] += a.x*w0 + a.y*w1 + a.z*w2 + a.w*w3;
            }
        }
        {
            float w0 = Wu1[488*HD+j];
#pragma unroll
            for (int k = 0; k < NBT; ++k) acc[k] += ui[k][488] * w0;
        }
        float bb = bu1[j];
#pragma unroll
        for (int k = 0; k < NBT; ++k) u1[k][j] = silu_f(acc[k] + bb);
    }
    __syncthreads();
    if (j < HD) {
        float acc[NBT] = {0.f, 0.f, 0.f, 0.f};
        for (int i4 = 0; i4 < 60; ++i4) {
            int i = 4 * i4;
            float w0 = Wu2[(i+0)*HD+j], w1 = Wu2[(i+1)*HD+j];
            float w2 = Wu2[(i+2)*HD+j], w3 = Wu2[(i+3)*HD+j];
#pragma unroll
            for (int k = 0; k < NBT; ++k) {
                const float4 a = *reinterpret_cast<const float4*>(&u1[k][i]);
                acc[k] += a.x*w0 + a.y*w1 + a.z*w2 + a.w*w3;
            }
        }
        float bb = bu2[j];
#pragma unroll
        for (int k = 0; k < NBT; ++k) h[(size_t)(n0 + k) * HD + j] += silu_f(acc[k] + bb);
    }
}

// ---------------- readout (grid nodes only) ----------------
__global__ void output_kernel(const float* __restrict__ h,
                              const float* __restrict__ Wo1, const float* __restrict__ bo1,
                              const float* __restrict__ Wo2, const float* __restrict__ bo2,
                              float* __restrict__ out) {
    const int NBT = 4;
    __shared__ float hr[NBT][HD];
    __shared__ float o1[NBT][HD];
    int tid = threadIdx.x;
    int g0 = blockIdx.x * NBT;
    for (int idx = tid; idx < NBT * HD; idx += 256) {
        int k = idx / HD, i = idx % HD;
        hr[k][i] = h[(size_t)(NA + g0 + k) * HD + i];
    }
    __syncthreads();
    int j = tid;
    if (j < HD) {
        float acc[NBT] = {0.f, 0.f, 0.f, 0.f};
        for (int i4 = 0; i4 < 60; ++i4) {
            int i = 4 * i4;
            float w0 = Wo1[(i+0)*HD+j], w1 = Wo1[(i+1)*HD+j];
            float w2 = Wo1[(i+2)*HD+j], w3 = Wo1[(i+3)*HD+j];
#pragma unroll
            for (int k = 0; k < NBT; ++k) {
                const float4 a = *reinterpret_cast<const float4*>(&hr[k][i]);
                acc[k] += a.x*w0 + a.y*w1 + a.z*w2 + a.w*w3;
            }
        }
        float bb = bo1[j];
#pragma unroll
        for (int k = 0; k < NBT; ++k) o1[k][j] = silu_f(acc[k] + bb);
    }
    __syncthreads();
    if (tid < NBT * CD) {
        int k = tid >> 5, c = tid & 31;
        float acc = bo2[c];
        for (int i = 0; i < HD; ++i) acc += o1[k][i] * Wo2[i*CD + c];
        out[(size_t)(g0 + k) * CD + c] = acc;
    }
}

extern "C" void kernel_launch(void* const* d_in, const int* in_sizes, int n_in,
                              void* d_out, int out_size, void* d_ws, size_t ws_size,
                              hipStream_t stream) {
    (void)in_sizes; (void)n_in; (void)out_size; (void)ws_size;
    const float* pos   = (const float*)d_in[0];
    const int*   types = (const int*)d_in[1];
    const int*   batch = (const int*)d_in[2];
    const float* We    = (const float*)d_in[3];
    const float* be    = (const float*)d_in[4];
    const float* Wm1   = (const float*)d_in[5];
    const float* bm1   = (const float*)d_in[6];
    const float* Wm2   = (const float*)d_in[7];
    const float* bm2   = (const float*)d_in[8];
    const float* Wu1   = (const float*)d_in[9];
    const float* bu1   = (const float*)d_in[10];
    const float* Wu2   = (const float*)d_in[11];
    const float* bu2   = (const float*)d_in[12];
    const float* Wo1   = (const float*)d_in[13];
    const float* bo1   = (const float*)d_in[14];
    const float* Wo2   = (const float*)d_in[15];
    const float* bo2   = (const float*)d_in[16];
    float* out = (float*)d_out;

    char* ws = (char*)d_ws;
    size_t off = 0;
    auto take = [&](size_t bytes) -> char* {
        char* p = ws + off;
        off = (off + bytes + 255) & ~(size_t)255;
        return p;
    };
    int*   nbr   = (int*)take((size_t)EAE * 4);
    int*   nbg   = (int*)take((size_t)EGE * 4);
    float* ea    = (float*)take((size_t)ET * 9 * 4);
    float* emask = (float*)take((size_t)ET * 4);
    float* attr  = (float*)take((size_t)NN * 9 * 4);
    float* h     = (float*)take((size_t)NN * HD * 4);
    float* agg   = (float*)take((size_t)NN * HD * 4);
    float* zs    = (float*)take((size_t)NA * HD * 4);
    float* zd    = (float*)take((size_t)NN * HD * 4);
    short* wm2t  = (short*)take((size_t)2 * 240 * 256 * 2);

    knn_atoms_kernel<<<NA/32, 256, 0, stream>>>(pos, batch, nbr);
    knn_grid_kernel<<<NG/64, 256, 0, stream>>>(pos, batch, nbg);
    edge_kernel<<<ET/256, 256, 0, stream>>>(pos, nbr, nbg, ea, emask);
    node_attr_kernel<<<NN/256, 256, 0, stream>>>(ea, emask, attr);
    encoder_kernel<<<(NN*HD)/256, 256, 0, stream>>>(types, attr, We, be, h);
    convert_wm2_kernel<<<(2*240*256)/256, 256, 0, stream>>>(Wm2, wm2t);

    for (int l = 0; l < 2; ++l) {
        const float* wm1 = Wm1 + (size_t)l * DIN * HD;
        const float* bb1 = bm1 + l * HD;
        const float* wea = wm1 + (size_t)480 * HD;
        const short* w2t = wm2t + (size_t)l * 240 * 256;
        const float* bb2 = bm2 + l * HD;
        node_z_kernel<<<NN/8, 256, 0, stream>>>(h, wm1, bb1, zs, zd);
        msg_mfma_kernel<KAK, 8><<<NA*KAK/64, 192, 0, stream>>>(
            zs, zd, nbr, ea, emask, wea, w2t, bb2, agg, 0, 0);
        msg_mfma_kernel<KGK, 2><<<NG*KGK/48, 192, 0, stream>>>(
            zs, zd, nbg, ea, emask, wea, w2t, bb2, agg, NA, EAE);
        update_kernel<<<NN/4, 256, 0, stream>>>(h, agg, attr,
                                                Wu1 + (size_t)l * DIN * HD, bu1 + l * HD,
                                                Wu2 + (size_t)l * HD * HD, bu2 + l * HD);
    }
    output_kernel<<<NG/4, 256, 0, stream>>>(h, Wo1, bo1, Wo2, bo2, out);
}

// Round 5
// 760.421 us; speedup vs baseline: 4.1437x; 1.3878x over previous
//
#include <hip/hip_runtime.h>
#include <math.h>

#define NA   1024
#define NGRID 4096
#define NB   2
#define NG   (NB*NGRID)   // 8192
#define NN   (NA+NG)      // 9216
#define KAK  8
#define KGK  24
#define EAE  (NA*KAK)     // 8192
#define EGE  (NG*KGK)     // 196608
#define ET   (EAE+EGE)    // 204800
#define HD   240
#define TT   16
#define DIN  489
#define CD   32
#define CUTF 8.0f

typedef __attribute__((ext_vector_type(8))) short short8;
typedef __attribute__((ext_vector_type(4))) short short4v;
typedef __attribute__((ext_vector_type(4))) float f32x4;

__device__ __forceinline__ float silu_f(float x) {
    return x / (1.0f + __expf(-x));
}
__device__ __forceinline__ short f2bf(float x) {  // RNE f32->bf16
    unsigned u = __float_as_uint(x);
    unsigned r = (u + 0x7FFFu + ((u >> 16) & 1u)) >> 16;
    return (short)r;
}

// ---------------- kNN, wave-per-query, register top-K ----------------
// Key = (d2_bits << 10) | atom_index : unique, IEEE-positive order == uint order,
// ties at equal d2 resolve to lower index == stable jax.lax.top_k order.
template <int K>
__device__ __forceinline__ void wave_topk(unsigned long long key[8], int lane,
                                          int* __restrict__ outp) {
    unsigned long long lmin = key[0];
#pragma unroll
    for (int s = 1; s < 8; ++s) lmin = key[s] < lmin ? key[s] : lmin;
    int myout = -1;
    for (int t = 0; t < K; ++t) {
        unsigned long long m = lmin;
#pragma unroll
        for (int d = 1; d < 64; d <<= 1) {
            unsigned long long o = __shfl_xor(m, d);
            m = o < m ? o : m;
        }
        if (lane == t) myout = (int)(m & 1023u);
        if (m == lmin) {  // unique keys -> exactly one owner lane
#pragma unroll
            for (int s = 0; s < 8; ++s) if (key[s] == m) key[s] = ~0ull;
            lmin = key[0];
#pragma unroll
            for (int s = 1; s < 8; ++s) lmin = key[s] < lmin ? key[s] : lmin;
        }
    }
    if (lane < K) outp[lane] = myout;
}

__global__ __launch_bounds__(256) void knn_atoms_kernel(const float* __restrict__ pos,
                                                        int* __restrict__ nbr) {
    __shared__ float sx[512], sy[512], sz[512];
    int tid = threadIdx.x;
    int q0 = blockIdx.x * 4;                    // 4 queries per block, never straddles halves
    int pbase = (q0 >= 512) ? 512 : 0;
    for (int j = tid; j < 512; j += 256) {
        sx[j] = pos[(pbase + j)*3 + 0];
        sy[j] = pos[(pbase + j)*3 + 1];
        sz[j] = pos[(pbase + j)*3 + 2];
    }
    __syncthreads();
    int lane = tid & 63;
    int i = q0 + (tid >> 6);
    float px = sx[i - pbase], py = sy[i - pbase], pz = sz[i - pbase];
    unsigned long long key[8];
#pragma unroll
    for (int s = 0; s < 8; ++s) {
        int c = s * 64 + lane;
        int j = pbase + c;
        float dx = px - sx[c], dy = py - sy[c], dz = pz - sz[c];
        float d2 = __fadd_rn(__fadd_rn(__fmul_rn(dx,dx), __fmul_rn(dy,dy)), __fmul_rn(dz,dz));
        key[s] = ((unsigned long long)__float_as_uint(d2) << 10) | (unsigned)j;
        if (j == i) key[s] = ~0ull;             // exclude self
    }
    wave_topk<KAK>(key, lane, &nbr[i*KAK]);
}

__global__ __launch_bounds__(256) void knn_grid_kernel(const float* __restrict__ pos,
                                                       int* __restrict__ nbg) {
    __shared__ float sx[512], sy[512], sz[512];
    int tid = threadIdx.x;
    int q0 = blockIdx.x * 4;                    // 4 grid queries per block
    int pbase = (q0 >= NGRID) ? 512 : 0;        // batch of this block's queries
    for (int j = tid; j < 512; j += 256) {
        sx[j] = pos[(pbase + j)*3 + 0];
        sy[j] = pos[(pbase + j)*3 + 1];
        sz[j] = pos[(pbase + j)*3 + 2];
    }
    __syncthreads();
    int lane = tid & 63;
    int g = q0 + (tid >> 6);
    int gi = g & (NGRID - 1);
    int ix = gi >> 8, iy = (gi >> 4) & 15, iz = gi & 15;
    float px = ((float)ix - 7.5f) * 1.5f;
    float py = ((float)iy - 7.5f) * 1.5f;
    float pz = ((float)iz - 7.5f) * 1.5f;
    unsigned long long key[8];
#pragma unroll
    for (int s = 0; s < 8; ++s) {
        int c = s * 64 + lane;
        int j = pbase + c;
        float dx = px - sx[c], dy = py - sy[c], dz = pz - sz[c];
        float d2 = __fadd_rn(__fadd_rn(__fmul_rn(dx,dx), __fmul_rn(dy,dy)), __fmul_rn(dz,dz));
        key[s] = ((unsigned long long)__float_as_uint(d2) << 10) | (unsigned)j;
    }
    wave_topk<KGK>(key, lane, &nbg[g*KGK]);
}

// ---------------- edge features (sph * mask) ----------------
__global__ void edge_kernel(const float* __restrict__ pos, const int* __restrict__ nbr,
                            const int* __restrict__ nbg, float* __restrict__ ea,
                            float* __restrict__ emask) {
    int e = blockIdx.x * blockDim.x + threadIdx.x;
    if (e >= ET) return;
    int src; float dpx, dpy, dpz;
    if (e < EAE) {
        int d = e >> 3;
        src = nbr[e];
        dpx = pos[d*3]; dpy = pos[d*3+1]; dpz = pos[d*3+2];
    } else {
        int eg = e - EAE;
        src = nbg[eg];
        int gg = eg / KGK;
        int gi = gg % NGRID;
        int ix = gi >> 8, iy = (gi >> 4) & 15, iz = gi & 15;
        dpx = ((float)ix - 7.5f) * 1.5f;
        dpy = ((float)iy - 7.5f) * 1.5f;
        dpz = ((float)iz - 7.5f) * 1.5f;
    }
    float rx = pos[src*3] - dpx, ry = pos[src*3+1] - dpy, rz = pos[src*3+2] - dpz;
    float dist = sqrtf(rx*rx + ry*ry + rz*rz);
    float mask = (dist <= CUTF) ? 1.0f : 0.0f;
    float inv = 1.0f / fmaxf(dist, 1e-9f);
    float x = rx * inv, y = ry * inv, z = rz * inv;
    float s0 = 0.28209479177387814f;
    float s1 = 0.4886025119029199f * y;
    float s2 = 0.4886025119029199f * z;
    float s3 = 0.4886025119029199f * x;
    float s4 = 1.0925484305920792f * x * y;
    float s5 = 1.0925484305920792f * y * z;
    float s6 = 0.31539156525252005f * (3.0f * z * z - 1.0f);
    float s7 = 1.0925484305920792f * z * x;
    float s8 = 0.5462742152960396f * (x * x - y * y);
    float* o = &ea[(size_t)e * 9];
    o[0] = s0 * mask; o[1] = s1 * mask; o[2] = s2 * mask; o[3] = s3 * mask;
    o[4] = s4 * mask; o[5] = s5 * mask; o[6] = s6 * mask; o[7] = s7 * mask; o[8] = s8 * mask;
    emask[e] = mask;
}

// ---------------- node_attr (segment mean of ea) ----------------
__global__ void node_attr_kernel(const float* __restrict__ ea, const float* __restrict__ emask,
                                 float* __restrict__ attr) {
    int n = blockIdx.x * blockDim.x + threadIdx.x;
    if (n >= NN) return;
    int K, e0;
    if (n < NA) { K = KAK; e0 = n * KAK; }
    else        { K = KGK; e0 = EAE + (n - NA) * KGK; }
    float s[9];
#pragma unroll
    for (int a = 0; a < 9; ++a) s[a] = 0.f;
    float cnt = 0.f;
    for (int k = 0; k < K; ++k) {
        cnt += emask[e0 + k];
        const float* p = &ea[(size_t)(e0 + k) * 9];
#pragma unroll
        for (int a = 0; a < 9; ++a) s[a] += p[a];
    }
    float invc = 1.0f / fmaxf(cnt, 1.0f);
    attr[n*9+0] = 1.0f;
#pragma unroll
    for (int a = 1; a < 9; ++a) attr[n*9+a] = s[a] * invc;
}

// ---------------- encoder: h = silu([feat|attr] @ We + be) ----------------
__global__ void encoder_kernel(const int* __restrict__ types, const float* __restrict__ attr,
                               const float* __restrict__ We, const float* __restrict__ be,
                               float* __restrict__ h) {
    int idx = blockIdx.x * blockDim.x + threadIdx.x;  // n*HD + j
    int n = idx / HD, j = idx % HD;
    float acc = be[j];
    if (n < NA) acc += We[types[n] * HD + j];
#pragma unroll
    for (int a = 0; a < 9; ++a) acc += attr[n*9+a] * We[(TT + a) * HD + j];
    h[idx] = silu_f(acc);
}

// ---------------- Wm2 -> bf16, transposed & K-padded: wm2t[l][col][k(256)] ----------------
__global__ void convert_wm2_kernel(const float* __restrict__ Wm2, short* __restrict__ wm2t) {
    int idx = blockIdx.x * blockDim.x + threadIdx.x;  // < 2*240*256
    int l = idx / (240*256);
    int rem = idx % (240*256);
    int col = rem / 256, k = rem % 256;
    short v = 0;
    if (k < 240) v = f2bf(Wm2[(size_t)l*57600 + k*240 + col]);
    wm2t[idx] = v;
}

// ---------------- per-node partial GEMMs: Zd = h@Wm1[240:480]+bm1 ; Zs = h@Wm1[0:240] (atoms only) ----------------
__global__ void node_z_kernel(const float* __restrict__ h, const float* __restrict__ Wm1,
                              const float* __restrict__ bm1,
                              float* __restrict__ Zs, float* __restrict__ Zd) {
    const int NBT = 8;
    __shared__ float hs[NBT*HD];
    int tid = threadIdx.x;
    int n0 = blockIdx.x * NBT;
    for (int idx = tid; idx < NBT*HD; idx += 256)
        hs[idx] = h[(size_t)n0*HD + idx];
    __syncthreads();
    int j = tid;
    if (j >= HD) return;
    if (n0 < NA) {
        float zd[NBT], zs[NBT];
        float b = bm1[j];
#pragma unroll
        for (int k = 0; k < NBT; ++k) { zd[k] = b; zs[k] = 0.f; }
        for (int i = 0; i < HD; ++i) {
            float wd = Wm1[(240 + i)*HD + j];
            float ws = Wm1[i*HD + j];
#pragma unroll
            for (int k = 0; k < NBT; ++k) {
                float hv = hs[k*HD + i];
                zd[k] += hv * wd;
                zs[k] += hv * ws;
            }
        }
#pragma unroll
        for (int k = 0; k < NBT; ++k) {
            Zd[(size_t)(n0 + k)*HD + j] = zd[k];
            Zs[(size_t)(n0 + k)*HD + j] = zs[k];
        }
    } else {
        float zd[NBT];
        float b = bm1[j];
#pragma unroll
        for (int k = 0; k < NBT; ++k) zd[k] = b;
        for (int i = 0; i < HD; ++i) {
            float wd = Wm1[(240 + i)*HD + j];
#pragma unroll
            for (int k = 0; k < NBT; ++k) zd[k] += hs[k*HD + i] * wd;
        }
#pragma unroll
        for (int k = 0; k < NBT; ++k) Zd[(size_t)(n0 + k)*HD + j] = zd[k];
    }
}

// ---------------- fused message MLP: assemble m1 (bf16) -> MFMA m1@Wm2 -> silu*mask -> per-node sum ----------------
template <int KE, int NPB>
__global__ __launch_bounds__(192) void msg_mfma_kernel(
        const float* __restrict__ Zs, const float* __restrict__ Zd,
        const int* __restrict__ nbrList, const float* __restrict__ ea,
        const float* __restrict__ emask, const float* __restrict__ Wea,
        const short* __restrict__ wm2t, const float* __restrict__ bm2,
        float* __restrict__ agg, int dstBase, int edgeBase) {
    constexpr int ROWS = KE * NPB;     // 48 or 64
    constexpr int MT = ROWS / 16;      // 3 or 4
    __shared__ __align__(16) short Abuf[ROWS * 264];  // m1 tile, K padded to 256 (+8 bank pad)
    __shared__ __align__(16) float mkbuf[ROWS];

    int tid = threadIdx.x;
    int b = blockIdx.x;
    int e0 = edgeBase + b * ROWS;

    if (tid < ROWS) mkbuf[tid] = emask[e0 + tid];
    for (int idx = tid; idx < ROWS * 24; idx += 192) {
        int r = idx / 24;
        Abuf[r * 264 + 240 + (idx % 24)] = 0;
    }
    for (int idx = tid; idx < ROWS * 60; idx += 192) {
        int row = idx / 60;
        int j = (idx % 60) * 4;
        int srcn = nbrList[b * ROWS + row];
        int dstn = dstBase + b * NPB + row / KE;
        const float4 zs = *(const float4*)(Zs + (size_t)srcn * HD + j);
        const float4 zd = *(const float4*)(Zd + (size_t)dstn * HD + j);
        float s0 = zs.x + zd.x, s1 = zs.y + zd.y, s2 = zs.z + zd.z, s3 = zs.w + zd.w;
        const float* ep = ea + (size_t)(e0 + row) * 9;
#pragma unroll
        for (int a = 0; a < 9; ++a) {
            float ev = ep[a];
            const float4 w = *(const float4*)(Wea + a * HD + j);
            s0 += ev * w.x; s1 += ev * w.y; s2 += ev * w.z; s3 += ev * w.w;
        }
        short4v o;
        o.x = f2bf(silu_f(s0)); o.y = f2bf(silu_f(s1));
        o.z = f2bf(silu_f(s2)); o.w = f2bf(silu_f(s3));
        *(short4v*)&Abuf[row * 264 + j] = o;
    }
    __syncthreads();

    int w = tid / 64, lane = tid % 64;
    int lg = lane >> 4, lc = lane & 15;
    int wcol0 = w * 80;

    f32x4 acc[MT][5];
#pragma unroll
    for (int mt = 0; mt < MT; ++mt)
#pragma unroll
        for (int nt = 0; nt < 5; ++nt) acc[mt][nt] = (f32x4){0.f, 0.f, 0.f, 0.f};

#pragma unroll
    for (int kc = 0; kc < 8; ++kc) {
        short8 af[MT];
#pragma unroll
        for (int mt = 0; mt < MT; ++mt)
            af[mt] = *(const short8*)&Abuf[(mt * 16 + lc) * 264 + kc * 32 + lg * 8];
#pragma unroll
        for (int nt = 0; nt < 5; ++nt) {
            const short8 bf = *(const short8*)(wm2t + (size_t)(wcol0 + nt * 16 + lc) * 256 + kc * 32 + lg * 8);
#pragma unroll
            for (int mt = 0; mt < MT; ++mt)
                acc[mt][nt] = __builtin_amdgcn_mfma_f32_16x16x32_bf16(af[mt], bf, acc[mt][nt], 0, 0, 0);
        }
    }

#pragma unroll
    for (int nt = 0; nt < 5; ++nt) {
        int ncol = wcol0 + nt * 16 + lc;
        float bias = bm2[ncol];
        float p[MT];
#pragma unroll
        for (int mt = 0; mt < MT; ++mt) {
            const float4 mkv = *(const float4*)&mkbuf[mt * 16 + lg * 4];
            float t0 = silu_f(acc[mt][nt].x + bias) * mkv.x;
            float t1 = silu_f(acc[mt][nt].y + bias) * mkv.y;
            float t2 = silu_f(acc[mt][nt].z + bias) * mkv.z;
            float t3 = silu_f(acc[mt][nt].w + bias) * mkv.w;
            p[mt] = (t0 + t1) + (t2 + t3);
        }
        if (KE == 24) {
            float v0 = p[0] + ((lg < 2) ? p[1] : 0.f);
            float v1 = ((lg >= 2) ? p[1] : 0.f) + p[2];
            v0 += __shfl_xor(v0, 16); v0 += __shfl_xor(v0, 32);
            v1 += __shfl_xor(v1, 16); v1 += __shfl_xor(v1, 32);
            if (lane < 16)      agg[(size_t)(dstBase + b * 2 + 0) * HD + ncol] = v0;
            else if (lane < 32) agg[(size_t)(dstBase + b * 2 + 1) * HD + ncol] = v1;
        } else {
#pragma unroll
            for (int mt = 0; mt < MT; ++mt) {
                float v = p[mt];
                v += __shfl_xor(v, 16);
                if (lane < 16)
                    agg[(size_t)(dstBase + b * (2 * MT) + 2 * mt + 0) * HD + ncol] = v;
                else if (lane >= 32 && lane < 48)
                    agg[(size_t)(dstBase + b * (2 * MT) + 2 * mt + 1) * HD + ncol] = v;
            }
        }
    }
}

// ---------------- node update: h += MLP([h|agg|attr]) ----------------
__global__ void update_kernel(float* __restrict__ h, const float* __restrict__ agg,
                              const float* __restrict__ attr,
                              const float* __restrict__ Wu1, const float* __restrict__ bu1,
                              const float* __restrict__ Wu2, const float* __restrict__ bu2) {
    const int NBT = 4;
    __shared__ float ui[NBT][492];
    __shared__ float u1[NBT][HD];
    int tid = threadIdx.x;
    int n0 = blockIdx.x * NBT;
    for (int idx = tid; idx < NBT * 492; idx += 256) {
        int k = idx / 492, i = idx % 492;
        int n = n0 + k;
        float v;
        if (i < 240)      v = h[(size_t)n * HD + i];
        else if (i < 480) v = agg[(size_t)n * HD + (i - 240)];
        else if (i < 489) v = attr[n*9 + (i - 480)];
        else              v = 0.f;
        ui[k][i] = v;
    }
    __syncthreads();
    int j = tid;
    if (j < HD) {
        float acc[NBT] = {0.f, 0.f, 0.f, 0.f};
        for (int i4 = 0; i4 < 122; ++i4) {
            int i = 4 * i4;
            float w0 = Wu1[(i+0)*HD+j], w1 = Wu1[(i+1)*HD+j];
            float w2 = Wu1[(i+2)*HD+j], w3 = Wu1[(i+3)*HD+j];
#pragma unroll
            for (int k = 0; k < NBT; ++k) {
                const float4 a = *reinterpret_cast<const float4*>(&ui[k][i]);
                acc[k] += a.x*w0 + a.y*w1 + a.z*w2 + a.w*w3;
            }
        }
        {
            float w0 = Wu1[488*HD+j];
#pragma unroll
            for (int k = 0; k < NBT; ++k) acc[k] += ui[k][488] * w0;
        }
        float bb = bu1[j];
#pragma unroll
        for (int k = 0; k < NBT; ++k) u1[k][j] = silu_f(acc[k] + bb);
    }
    __syncthreads();
    if (j < HD) {
        float acc[NBT] = {0.f, 0.f, 0.f, 0.f};
        for (int i4 = 0; i4 < 60; ++i4) {
            int i = 4 * i4;
            float w0 = Wu2[(i+0)*HD+j], w1 = Wu2[(i+1)*HD+j];
            float w2 = Wu2[(i+2)*HD+j], w3 = Wu2[(i+3)*HD+j];
#pragma unroll
            for (int k = 0; k < NBT; ++k) {
                const float4 a = *reinterpret_cast<const float4*>(&u1[k][i]);
                acc[k] += a.x*w0 + a.y*w1 + a.z*w2 + a.w*w3;
            }
        }
        float bb = bu2[j];
#pragma unroll
        for (int k = 0; k < NBT; ++k) h[(size_t)(n0 + k) * HD + j] += silu_f(acc[k] + bb);
    }
}

// ---------------- readout (grid nodes only) ----------------
__global__ void output_kernel(const float* __restrict__ h,
                              const float* __restrict__ Wo1, const float* __restrict__ bo1,
                              const float* __restrict__ Wo2, const float* __restrict__ bo2,
                              float* __restrict__ out) {
    const int NBT = 4;
    __shared__ float hr[NBT][HD];
    __shared__ float o1[NBT][HD];
    int tid = threadIdx.x;
    int g0 = blockIdx.x * NBT;
    for (int idx = tid; idx < NBT * HD; idx += 256) {
        int k = idx / HD, i = idx % HD;
        hr[k][i] = h[(size_t)(NA + g0 + k) * HD + i];
    }
    __syncthreads();
    int j = tid;
    if (j < HD) {
        float acc[NBT] = {0.f, 0.f, 0.f, 0.f};
        for (int i4 = 0; i4 < 60; ++i4) {
            int i = 4 * i4;
            float w0 = Wo1[(i+0)*HD+j], w1 = Wo1[(i+1)*HD+j];
            float w2 = Wo1[(i+2)*HD+j], w3 = Wo1[(i+3)*HD+j];
#pragma unroll
            for (int k = 0; k < NBT; ++k) {
                const float4 a = *reinterpret_cast<const float4*>(&hr[k][i]);
                acc[k] += a.x*w0 + a.y*w1 + a.z*w2 + a.w*w3;
            }
        }
        float bb = bo1[j];
#pragma unroll
        for (int k = 0; k < NBT; ++k) o1[k][j] = silu_f(acc[k] + bb);
    }
    __syncthreads();
    if (tid < NBT * CD) {
        int k = tid >> 5, c = tid & 31;
        float acc = bo2[c];
        for (int i = 0; i < HD; ++i) acc += o1[k][i] * Wo2[i*CD + c];
        out[(size_t)(g0 + k) * CD + c] = acc;
    }
}

extern "C" void kernel_launch(void* const* d_in, const int* in_sizes, int n_in,
                              void* d_out, int out_size, void* d_ws, size_t ws_size,
                              hipStream_t stream) {
    (void)in_sizes; (void)n_in; (void)out_size; (void)ws_size;
    const float* pos   = (const float*)d_in[0];
    const int*   types = (const int*)d_in[1];
    const int*   batch = (const int*)d_in[2];
    (void)batch;
    const float* We    = (const float*)d_in[3];
    const float* be    = (const float*)d_in[4];
    const float* Wm1   = (const float*)d_in[5];
    const float* bm1   = (const float*)d_in[6];
    const float* Wm2   = (const float*)d_in[7];
    const float* bm2   = (const float*)d_in[8];
    const float* Wu1   = (const float*)d_in[9];
    const float* bu1   = (const float*)d_in[10];
    const float* Wu2   = (const float*)d_in[11];
    const float* bu2   = (const float*)d_in[12];
    const float* Wo1   = (const float*)d_in[13];
    const float* bo1   = (const float*)d_in[14];
    const float* Wo2   = (const float*)d_in[15];
    const float* bo2   = (const float*)d_in[16];
    float* out = (float*)d_out;

    char* ws = (char*)d_ws;
    size_t off = 0;
    auto take = [&](size_t bytes) -> char* {
        char* p = ws + off;
        off = (off + bytes + 255) & ~(size_t)255;
        return p;
    };
    int*   nbr   = (int*)take((size_t)EAE * 4);
    int*   nbg   = (int*)take((size_t)EGE * 4);
    float* ea    = (float*)take((size_t)ET * 9 * 4);
    float* emask = (float*)take((size_t)ET * 4);
    float* attr  = (float*)take((size_t)NN * 9 * 4);
    float* h     = (float*)take((size_t)NN * HD * 4);
    float* agg   = (float*)take((size_t)NN * HD * 4);
    float* zs    = (float*)take((size_t)NA * HD * 4);
    float* zd    = (float*)take((size_t)NN * HD * 4);
    short* wm2t  = (short*)take((size_t)2 * 240 * 256 * 2);

    knn_atoms_kernel<<<NA/4, 256, 0, stream>>>(pos, nbr);
    knn_grid_kernel<<<NG/4, 256, 0, stream>>>(pos, nbg);
    edge_kernel<<<ET/256, 256, 0, stream>>>(pos, nbr, nbg, ea, emask);
    node_attr_kernel<<<NN/256, 256, 0, stream>>>(ea, emask, attr);
    encoder_kernel<<<(NN*HD)/256, 256, 0, stream>>>(types, attr, We, be, h);
    convert_wm2_kernel<<<(2*240*256)/256, 256, 0, stream>>>(Wm2, wm2t);

    for (int l = 0; l < 2; ++l) {
        const float* wm1 = Wm1 + (size_t)l * DIN * HD;
        const float* bb1 = bm1 + l * HD;
        const float* wea = wm1 + (size_t)480 * HD;
        const short* w2t = wm2t + (size_t)l * 240 * 256;
        const float* bb2 = bm2 + l * HD;
        node_z_kernel<<<NN/8, 256, 0, stream>>>(h, wm1, bb1, zs, zd);
        msg_mfma_kernel<KAK, 8><<<NA*KAK/64, 192, 0, stream>>>(
            zs, zd, nbr, ea, emask, wea, w2t, bb2, agg, 0, 0);
        msg_mfma_kernel<KGK, 2><<<NG*KGK/48, 192, 0, stream>>>(
            zs, zd, nbg, ea, emask, wea, w2t, bb2, agg, NA, EAE);
        update_kernel<<<NN/4, 256, 0, stream>>>(h, agg, attr,
                                                Wu1 + (size_t)l * DIN * HD, bu1 + l * HD,
                                                Wu2 + (size_t)l * HD * HD, bu2 + l * HD);
    }
    output_kernel<<<NG/4, 256, 0, stream>>>(h, Wo1, bo1, Wo2, bo2, out);
}